// Round 1
// baseline (1492.311 us; speedup 1.0000x reference)
//
#include <hip/hip_runtime.h>
#include <stdint.h>

#define B_  2
#define H_  8
#define S_  4096
#define DM_ 512
#define DK_ 64
#define BH_ (B_*H_)

using f32x4 = __attribute__((ext_vector_type(4))) float;
using s16x8 = __attribute__((ext_vector_type(8))) short;
using u16x4 = __attribute__((ext_vector_type(4))) unsigned short;

__device__ __forceinline__ unsigned short f2bf(float f) {
    unsigned int u = __float_as_uint(f);
    u += 0x7FFFu + ((u >> 16) & 1u);          // RNE
    return (unsigned short)(u >> 16);
}
__device__ __forceinline__ float bf2f(unsigned short h) {
    return __uint_as_float(((unsigned int)h) << 16);
}

// ---------------------------------------------------------------------------
// Projection GEMM: Y[m][n] = (sum_k X[m][k]*W[n][k] + bias[n]) * scale
// hi/lo bf16 split (3 MFMAs) for fp32-quality result, output bf16.
// MODE 0: Y stored [b][h][s][d]   (q, k)
// MODE 1: Y stored [b][h][d][s]   (v transposed, for PV B-operand)
// ---------------------------------------------------------------------------
template<int MODE>
__global__ __launch_bounds__(256) void proj_kernel(
        const float* __restrict__ X, const float* __restrict__ W,
        const float* __restrict__ bias, unsigned short* __restrict__ Y,
        float scale)
{
    __shared__ __align__(16) unsigned short xh[64*40], xl[64*40];
    __shared__ __align__(16) unsigned short wh[64*40], wl[64*40];
    const int tid  = threadIdx.x;
    const int wave = tid >> 6, lane = tid & 63, lq = lane >> 4, lr = lane & 15;
    const int m0 = blockIdx.x * 64, n0 = blockIdx.y * 64;

    f32x4 acc[4] = {{0.f,0.f,0.f,0.f},{0.f,0.f,0.f,0.f},
                    {0.f,0.f,0.f,0.f},{0.f,0.f,0.f,0.f}};

    for (int kk = 0; kk < 16; ++kk) {
        __syncthreads();
#pragma unroll
        for (int p = 0; p < 2; ++p) {
            int idx = tid + p*256;
            int row = idx >> 3, seg = idx & 7;
            float4 xv = *(const float4*)&X[(size_t)(m0+row)*DM_ + kk*32 + seg*4];
            float4 wv = *(const float4*)&W[(size_t)(n0+row)*DM_ + kk*32 + seg*4];
            float xs4[4] = {xv.x, xv.y, xv.z, xv.w};
            float ws4[4] = {wv.x, wv.y, wv.z, wv.w};
            u16x4 xhi, xlo, whi, wlo;
#pragma unroll
            for (int i = 0; i < 4; ++i) {
                unsigned short h = f2bf(xs4[i]); xhi[i] = h; xlo[i] = f2bf(xs4[i] - bf2f(h));
                unsigned short g = f2bf(ws4[i]); whi[i] = g; wlo[i] = f2bf(ws4[i] - bf2f(g));
            }
            *(u16x4*)&xh[row*40 + seg*4] = xhi;
            *(u16x4*)&xl[row*40 + seg*4] = xlo;
            *(u16x4*)&wh[row*40 + seg*4] = whi;
            *(u16x4*)&wl[row*40 + seg*4] = wlo;
        }
        __syncthreads();
        const int ar = wave*16 + lr;
        s16x8 ah = *(const s16x8*)&xh[ar*40 + lq*8];
        s16x8 al = *(const s16x8*)&xl[ar*40 + lq*8];
#pragma unroll
        for (int nt = 0; nt < 4; ++nt) {
            int br = nt*16 + lr;
            s16x8 bh8 = *(const s16x8*)&wh[br*40 + lq*8];
            s16x8 bl8 = *(const s16x8*)&wl[br*40 + lq*8];
            acc[nt] = __builtin_amdgcn_mfma_f32_16x16x32_bf16(ah, bh8, acc[nt], 0, 0, 0);
            acc[nt] = __builtin_amdgcn_mfma_f32_16x16x32_bf16(ah, bl8, acc[nt], 0, 0, 0);
            acc[nt] = __builtin_amdgcn_mfma_f32_16x16x32_bf16(al, bh8, acc[nt], 0, 0, 0);
        }
    }
#pragma unroll
    for (int nt = 0; nt < 4; ++nt)
#pragma unroll
        for (int r = 0; r < 4; ++r) {
            int m = m0 + wave*16 + lq*4 + r;
            int n = n0 + nt*16 + lr;
            float v = (acc[nt][r] + bias[n]) * scale;
            int b = m >> 12, s = m & 4095;
            int h = n >> 6,  d = n & 63;
            size_t addr;
            if (MODE == 0) addr = ((size_t)((b*H_ + h)*S_ + s))*DK_ + d;
            else           addr = ((size_t)((b*H_ + h)*DK_ + d))*S_ + s;
            Y[addr] = f2bf(v);
        }
}

// ---------------------------------------------------------------------------
// Stats pass: l[bh][sq] = sum_{j<=sq} exp(s(sq,j) - 16). Same MFMA as pass 2,
// so l is *exactly* the sum of the p values pass 2 writes.
// ---------------------------------------------------------------------------
__global__ __launch_bounds__(256) void stats_kernel(
        const unsigned short* __restrict__ qb, const unsigned short* __restrict__ kb,
        float* __restrict__ lsum)
{
    __shared__ __align__(16) unsigned short qs[64*72], ks[32*72];
    const int tid  = threadIdx.x;
    const int wave = tid >> 6, lane = tid & 63, lq = lane >> 4, lr = lane & 15;
    const int bh = blockIdx.y;
    const int s0 = blockIdx.x * 64;

#pragma unroll
    for (int p = 0; p < 2; ++p) {
        int idx = tid + p*256;
        int row = idx >> 3, seg = idx & 7;
        *(s16x8*)&qs[row*72 + seg*8] =
            *(const s16x8*)&qb[((size_t)bh*S_ + s0 + row)*DK_ + seg*8];
    }
    __syncthreads();
    const int ar = wave*16 + lr;
    s16x8 aq0 = *(const s16x8*)&qs[ar*72 +  0 + lq*8];
    s16x8 aq1 = *(const s16x8*)&qs[ar*72 + 32 + lq*8];

    float lacc[4] = {0.f, 0.f, 0.f, 0.f};
    const int jtmax = (s0 + 63) >> 5;
    for (int jt = 0; jt <= jtmax; ++jt) {
        __syncthreads();
        {
            int row = tid >> 3, seg = tid & 7;
            *(s16x8*)&ks[row*72 + seg*8] =
                *(const s16x8*)&kb[((size_t)bh*S_ + jt*32 + row)*DK_ + seg*8];
        }
        __syncthreads();
#pragma unroll
        for (int nt = 0; nt < 2; ++nt) {
            int br = nt*16 + lr;
            s16x8 b0 = *(const s16x8*)&ks[br*72 +  0 + lq*8];
            s16x8 b1 = *(const s16x8*)&ks[br*72 + 32 + lq*8];
            f32x4 sc = {0.f,0.f,0.f,0.f};
            sc = __builtin_amdgcn_mfma_f32_16x16x32_bf16(aq0, b0, sc, 0, 0, 0);
            sc = __builtin_amdgcn_mfma_f32_16x16x32_bf16(aq1, b1, sc, 0, 0, 0);
            int j = jt*32 + nt*16 + lr;
#pragma unroll
            for (int r = 0; r < 4; ++r) {
                int sq = s0 + wave*16 + lq*4 + r;
                lacc[r] += (j <= sq) ? __expf(sc[r] - 16.f) : 0.f;
            }
        }
    }
#pragma unroll
    for (int r = 0; r < 4; ++r) {
        float v = lacc[r];
        for (int off = 1; off < 16; off <<= 1) v += __shfl_xor(v, off, 64);
        if (lr == 0) lsum[(size_t)bh*S_ + s0 + wave*16 + lq*4 + r] = v;
    }
}

// ---------------------------------------------------------------------------
// Pass 2: recompute scores, attn = exp(s-16)/l, write attn (fp32, zeros above
// diagonal), LDS round-trip attn->A-frag, PV MFMA, store O as bf16 [b][s][hd].
// ---------------------------------------------------------------------------
__global__ __launch_bounds__(256) void attn_kernel(
        const unsigned short* __restrict__ qb, const unsigned short* __restrict__ kb,
        const unsigned short* __restrict__ vtb, const float* __restrict__ lsum,
        float* __restrict__ attn, unsigned short* __restrict__ oacc)
{
    __shared__ __align__(16) unsigned short qs[64*72], ks[32*72], vs[64*40];
    __shared__ __align__(16) unsigned short ps[4][16*40];
    __shared__ float invl[64];
    const int tid  = threadIdx.x;
    const int wave = tid >> 6, lane = tid & 63, lq = lane >> 4, lr = lane & 15;
    const int bh = blockIdx.y;
    const int s0 = blockIdx.x * 64;

#pragma unroll
    for (int p = 0; p < 2; ++p) {
        int idx = tid + p*256;
        int row = idx >> 3, seg = idx & 7;
        *(s16x8*)&qs[row*72 + seg*8] =
            *(const s16x8*)&qb[((size_t)bh*S_ + s0 + row)*DK_ + seg*8];
    }
    if (tid < 64) invl[tid] = 1.0f / lsum[(size_t)bh*S_ + s0 + tid];
    __syncthreads();
    const int ar = wave*16 + lr;
    s16x8 aq0 = *(const s16x8*)&qs[ar*72 +  0 + lq*8];
    s16x8 aq1 = *(const s16x8*)&qs[ar*72 + 32 + lq*8];
    float il[4];
#pragma unroll
    for (int r = 0; r < 4; ++r) il[r] = invl[wave*16 + lq*4 + r];

    f32x4 O[4] = {{0.f,0.f,0.f,0.f},{0.f,0.f,0.f,0.f},
                  {0.f,0.f,0.f,0.f},{0.f,0.f,0.f,0.f}};
    const int jtcomp = (s0 + 63) >> 5;

    for (int jt = 0; jt < S_/32; ++jt) {
        if (jt <= jtcomp) {
            __syncthreads();
            {
                int row = tid >> 3, seg = tid & 7;
                *(s16x8*)&ks[row*72 + seg*8] =
                    *(const s16x8*)&kb[((size_t)bh*S_ + jt*32 + row)*DK_ + seg*8];
            }
            {
                int d = tid >> 2, seg = tid & 3;
                *(s16x8*)&vs[d*40 + seg*8] =
                    *(const s16x8*)&vtb[((size_t)bh*DK_ + d)*S_ + jt*32 + seg*8];
            }
            __syncthreads();
#pragma unroll
            for (int nt = 0; nt < 2; ++nt) {
                int br = nt*16 + lr;
                s16x8 b0 = *(const s16x8*)&ks[br*72 +  0 + lq*8];
                s16x8 b1 = *(const s16x8*)&ks[br*72 + 32 + lq*8];
                f32x4 sc = {0.f,0.f,0.f,0.f};
                sc = __builtin_amdgcn_mfma_f32_16x16x32_bf16(aq0, b0, sc, 0, 0, 0);
                sc = __builtin_amdgcn_mfma_f32_16x16x32_bf16(aq1, b1, sc, 0, 0, 0);
                int j = jt*32 + nt*16 + lr;
#pragma unroll
                for (int r = 0; r < 4; ++r) {
                    int sq = s0 + wave*16 + lq*4 + r;
                    float p = (j <= sq) ? __expf(sc[r] - 16.f) : 0.f;
                    float a = p * il[r];
                    attn[((size_t)bh*S_ + sq)*S_ + j] = a;
                    ps[wave][(lq*4 + r)*40 + nt*16 + lr] = f2bf(a);
                }
            }
            __syncthreads();   // make ps visible across lanes (and reuse as block barrier)
            s16x8 ap = *(const s16x8*)&ps[wave][lr*40 + lq*8];
#pragma unroll
            for (int nt = 0; nt < 4; ++nt) {
                s16x8 bv = *(const s16x8*)&vs[(nt*16 + lr)*40 + lq*8];
                O[nt] = __builtin_amdgcn_mfma_f32_16x16x32_bf16(ap, bv, O[nt], 0, 0, 0);
            }
        } else {
            // fully-masked tile: fast zero fill (upper triangle must be 0.0f)
#pragma unroll
            for (int p = 0; p < 2; ++p) {
                int idx = tid + p*256;
                int row = idx >> 3, c4 = idx & 7;
                float4 z = {0.f, 0.f, 0.f, 0.f};
                *(float4*)&attn[((size_t)bh*S_ + s0 + row)*S_ + jt*32 + c4*4] = z;
            }
        }
    }
    const int b = bh >> 3, h = bh & 7;
#pragma unroll
    for (int nt = 0; nt < 4; ++nt)
#pragma unroll
        for (int r = 0; r < 4; ++r) {
            int s = s0 + wave*16 + lq*4 + r;
            oacc[((size_t)(b*S_ + s))*DM_ + h*DK_ + nt*16 + lr] = f2bf(O[nt][r]);
        }
}

// ---------------------------------------------------------------------------
// Output projection: out[m][n] = sum_k AttnOut[m][k]*Wo[n][k] + bo[n] (fp32 out)
// ---------------------------------------------------------------------------
__global__ __launch_bounds__(256) void outproj_kernel(
        const unsigned short* __restrict__ Xin, const float* __restrict__ W,
        const float* __restrict__ bias, float* __restrict__ out)
{
    __shared__ __align__(16) unsigned short xs[64*40], wh[64*40];
    const int tid  = threadIdx.x;
    const int wave = tid >> 6, lane = tid & 63, lq = lane >> 4, lr = lane & 15;
    const int m0 = blockIdx.x * 64, n0 = blockIdx.y * 64;

    f32x4 acc[4] = {{0.f,0.f,0.f,0.f},{0.f,0.f,0.f,0.f},
                    {0.f,0.f,0.f,0.f},{0.f,0.f,0.f,0.f}};

    for (int kk = 0; kk < 16; ++kk) {
        __syncthreads();
        {
            int row = tid >> 2, seg = tid & 3;
            *(s16x8*)&xs[row*40 + seg*8] =
                *(const s16x8*)&Xin[(size_t)(m0+row)*DM_ + kk*32 + seg*8];
        }
#pragma unroll
        for (int p = 0; p < 2; ++p) {
            int idx = tid + p*256;
            int row = idx >> 3, seg = idx & 7;
            float4 wv = *(const float4*)&W[(size_t)(n0+row)*DM_ + kk*32 + seg*4];
            u16x4 whi;
            whi[0] = f2bf(wv.x); whi[1] = f2bf(wv.y);
            whi[2] = f2bf(wv.z); whi[3] = f2bf(wv.w);
            *(u16x4*)&wh[row*40 + seg*4] = whi;
        }
        __syncthreads();
        s16x8 a = *(const s16x8*)&xs[(wave*16 + lr)*40 + lq*8];
#pragma unroll
        for (int nt = 0; nt < 4; ++nt) {
            s16x8 b = *(const s16x8*)&wh[(nt*16 + lr)*40 + lq*8];
            acc[nt] = __builtin_amdgcn_mfma_f32_16x16x32_bf16(a, b, acc[nt], 0, 0, 0);
        }
    }
#pragma unroll
    for (int nt = 0; nt < 4; ++nt)
#pragma unroll
        for (int r = 0; r < 4; ++r) {
            int m = m0 + wave*16 + lq*4 + r;
            int n = n0 + nt*16 + lr;
            out[(size_t)m*DM_ + n] = acc[nt][r] + bias[n];
        }
}

// ---------------------------------------------------------------------------
extern "C" void kernel_launch(void* const* d_in, const int* in_sizes, int n_in,
                              void* d_out, int out_size, void* d_ws, size_t ws_size,
                              hipStream_t stream)
{
    const float* Q  = (const float*)d_in[0];
    const float* K  = (const float*)d_in[1];
    const float* V  = (const float*)d_in[2];
    const float* Wq = (const float*)d_in[3];  const float* bq = (const float*)d_in[4];
    const float* Wk = (const float*)d_in[5];  const float* bk = (const float*)d_in[6];
    const float* Wv = (const float*)d_in[7];  const float* bv = (const float*)d_in[8];
    const float* Wo = (const float*)d_in[9];  const float* bo = (const float*)d_in[10];

    char* ws = (char*)d_ws;
    const size_t QKV_BYTES = (size_t)BH_ * S_ * DK_ * sizeof(unsigned short); // 8,388,608
    unsigned short* qbf  = (unsigned short*)(ws);
    unsigned short* kbf  = (unsigned short*)(ws + QKV_BYTES);
    unsigned short* vtb  = (unsigned short*)(ws + 2*QKV_BYTES);
    float*          lsum = (float*)(ws + 3*QKV_BYTES);                       // 262,144 B
    unsigned short* oacc = (unsigned short*)(ws + 3*QKV_BYTES + (size_t)BH_*S_*sizeof(float));

    float* out0 = (float*)d_out;
    float* attn = out0 + (size_t)B_ * S_ * DM_;

    dim3 blk(256);
    proj_kernel<0><<<dim3(128, 8), blk, 0, stream>>>(Q, Wq, bq, qbf, 0.125f); // 1/sqrt(dk) folded
    proj_kernel<0><<<dim3(128, 8), blk, 0, stream>>>(K, Wk, bk, kbf, 1.0f);
    proj_kernel<1><<<dim3(128, 8), blk, 0, stream>>>(V, Wv, bv, vtb, 1.0f);
    stats_kernel  <<<dim3(64, 16), blk, 0, stream>>>(qbf, kbf, lsum);
    attn_kernel   <<<dim3(64, 16), blk, 0, stream>>>(qbf, kbf, vtb, lsum, attn, oacc);
    outproj_kernel<<<dim3(128, 8), blk, 0, stream>>>(oacc, Wo, bo, out0);
}